// Round 12
// baseline (328.462 us; speedup 1.0000x reference)
//
#include <hip/hip_runtime.h>
#include <stdint.h>

typedef __attribute__((ext_vector_type(8))) short bf16x8;
typedef __attribute__((ext_vector_type(4))) float f32x4;

__device__ __forceinline__ ushort f2bf(float f) {
    union { float f; uint32_t i; } v; v.f = f;
    uint32_t r = v.i + 0x7fff + ((v.i >> 16) & 1);
    return (ushort)(r >> 16);
}
__device__ __forceinline__ uint32_t cvtpk(float lo, float hi) {
    uint32_t r;
    asm("v_cvt_pk_bf16_f32 %0, %1, %2" : "=v"(r) : "v"(lo), "v"(hi));
    return r;
}

typedef unsigned int uint_as1 __attribute__((address_space(1)));
typedef unsigned int uint_as3 __attribute__((address_space(3)));
__device__ __forceinline__ void async16(const void* g, void* l) {
    __builtin_amdgcn_global_load_lds((const uint_as1*)g, (uint_as3*)l, 16, 0, 0);
}

// ---------------- small prep kernels ----------------

__global__ void cvt_f32_bf16(const float* __restrict__ in, ushort* __restrict__ out, int n) {
    int i = blockIdx.x * blockDim.x + threadIdx.x;
    if (i < n) out[i] = f2bf(in[i]);
}

__global__ void prep_bn(const float* __restrict__ bk, const float* __restrict__ gamma,
                        const float* __restrict__ beta, const float* __restrict__ rmean,
                        const float* __restrict__ rvar,
                        float* __restrict__ scaleA, float* __restrict__ shiftA) {
    int i = threadIdx.x;  // 256 threads, 1 block
    float s = gamma[i] * rsqrtf(rvar[i] + 1e-5f);
    scaleA[i] = 0.25f * s;                                // fold Ck^-0.5 = 1/16 as 0.25 per operand
    shiftA[i] = 0.25f * ((bk[i] - rmean[i]) * s + beta[i]);
}

// x [b][512][6400] f32  ->  Xt [b][6400][512] bf16
__global__ void transpose_cvt(const float* __restrict__ x, ushort* __restrict__ xt) {
    __shared__ float t[32][33];
    int b = blockIdx.z;
    int n0 = blockIdx.x * 32, c0 = blockIdx.y * 32;
    const float* xb = x + (size_t)b * 512 * 6400;
    ushort* xtb = xt + (size_t)b * 6400 * 512;
    int tx = threadIdx.x, ty = threadIdx.y;
    t[ty][tx] = xb[(size_t)(c0 + ty) * 6400 + n0 + tx];
    __syncthreads();
    xtb[(size_t)(n0 + ty) * 512 + c0 + tx] = f2bf(t[tx][ty]);
}

// ---------------- unified NT GEMM: C[i][j] = sum_k A[i][k]*B[j][k] ----------------
// Round-6 proven core: 128x128 tile, 4 waves, BK=32, 3-buf LDS, counted vmcnt(4)
// + raw s_barrier per K-step. LDS quarter-swizzle (SQ_LDS_BANK_CONFLICT = 0).
// Epilogue repacks acc through LDS for full-line stores; bf16 via v_cvt_pk_bf16_f32.
// EPI 1: bf16 store relu(acc*vec0[col] + vec1[col])   (col-affine, BN+ReLU for Kt)
// EPI 2: bf16 store acc + vec0[row]                   (row bias, V)
// EPI 3: f32  store acc + vec0[row]                   (row bias, final out)
// EPI 6: SYMMETRIC exp tile (round-11 validated): bx >= by only; store exp(acc)
//        tile AND mirror; rsum[bx][rows] / rsum[by][cols] partials.
template <int EPI>
__global__ __launch_bounds__(256) void gemm_nt(
    const ushort* __restrict__ A, const ushort* __restrict__ B, void* __restrict__ Cout,
    int K, int lda, int ldb, int ldc,
    size_t zsa, size_t zsb, size_t zsc,
    const float* __restrict__ vec0, const float* __restrict__ vec1,
    float* __restrict__ rsum) {
    if (EPI == 6 && blockIdx.x < blockIdx.y) return;   // lower triangle: no-op

    __shared__ __align__(16) ushort smem[6 * 4096];

    A += (size_t)blockIdx.z * zsa;
    B += (size_t)blockIdx.z * zsb;

    const int tid = threadIdx.x;
    const int lane = tid & 63, wave = tid >> 6;
    const int wm = wave & 1, wn = wave >> 1;
    const int bM = blockIdx.y * 128, bN = blockIdx.x * 128;

    const int sr = lane >> 2;
    const int scs = ((lane & 3) ^ ((lane >> 3) & 3)) * 8;
    const ushort* gA0 = A + (size_t)(bM + wave * 32 + sr) * lda + scs;
    const ushort* gA1 = gA0 + (size_t)16 * lda;
    const ushort* gB0 = B + (size_t)(bN + wave * 32 + sr) * ldb + scs;
    const ushort* gB1 = gB0 + (size_t)16 * ldb;
    ushort* lAw = &smem[wave * 1024];
    ushort* lBw = &smem[3 * 4096 + wave * 1024];

    const int rowA = wm * 64;
    const int rowB = wn * 64;
    const int fr = lane & 15;
    const int fk = ((lane >> 4) ^ ((fr >> 1) & 3)) * 8;

    f32x4 acc[4][4] = {};
    const int nT = K >> 5;

    auto stage = [&](int t, int buf) {
        const int k0 = t * 32;
        const int ob = buf * 4096;
        async16(gA0 + k0, lAw + ob);
        async16(gA1 + k0, lAw + ob + 512);
        async16(gB0 + k0, lBw + ob);
        async16(gB1 + k0, lBw + ob + 512);
    };

    stage(0, 0);
    if (nT > 1) stage(1, 1);

    for (int t = 0; t < nT; ++t) {
        if (t + 1 < nT) { asm volatile("s_waitcnt vmcnt(4)" ::: "memory"); }
        else            { asm volatile("s_waitcnt vmcnt(0)" ::: "memory"); }
        __builtin_amdgcn_sched_barrier(0);
        __builtin_amdgcn_s_barrier();
        __builtin_amdgcn_sched_barrier(0);
        if (t + 2 < nT) stage(t + 2, (t + 2) % 3);
        const int cur = t % 3;
        const ushort* lA = &smem[cur * 4096];
        const ushort* lB = &smem[3 * 4096 + cur * 4096];
        bf16x8 af[4], bff[4];
#pragma unroll
        for (int mi = 0; mi < 4; mi++)
            af[mi] = *(const bf16x8*)&lA[(rowA + mi * 16 + fr) * 32 + fk];
#pragma unroll
        for (int ni = 0; ni < 4; ni++)
            bff[ni] = *(const bf16x8*)&lB[(rowB + ni * 16 + fr) * 32 + fk];
#pragma unroll
        for (int mi = 0; mi < 4; mi++)
#pragma unroll
            for (int ni = 0; ni < 4; ni++)
                acc[mi][ni] = __builtin_amdgcn_mfma_f32_16x16x32_bf16(af[mi], bff[ni], acc[mi][ni], 0, 0, 0);
        __builtin_amdgcn_sched_barrier(0);
    }
    __builtin_amdgcn_s_barrier();
    __builtin_amdgcn_sched_barrier(0);

    // ---- epilogue: repack through LDS, store full lines ----
    float* Cf = (float*)Cout + (size_t)blockIdx.z * zsc;
    ushort* Cu = (ushort*)Cout + (size_t)blockIdx.z * zsc;
    float* lt = (float*)smem;
    const int g4 = (lane >> 4) * 4;
    const int cl = lane & 15;
    const int lr = tid >> 3;
    const int ch = tid & 7;

    if (EPI == 6) {
        const bool diag = (blockIdx.x == blockIdx.y);
        float creg[16];
#pragma unroll
        for (int i = 0; i < 16; i++) creg[i] = 0.f;
#pragma unroll
        for (int mi = 0; mi < 4; ++mi) {
#pragma unroll
            for (int ni = 0; ni < 4; ++ni) {
                const int lcol = wn * 64 + ni * 16 + cl;
#pragma unroll
                for (int r = 0; r < 4; ++r)
                    lt[(wm * 16 + g4 + r) * 132 + lcol] = acc[mi][ni][r];
            }
            __syncthreads();
            const int brow = (lr < 16) ? (mi * 16 + lr) : (64 + mi * 16 + (lr - 16));
            const int grow = bM + brow;
            const int gcol = bN + ch * 16;
            float vv[16];
#pragma unroll
            for (int i = 0; i < 16; i += 4) {
                f32x4 q = *(const f32x4*)&lt[lr * 132 + ch * 16 + i];
                vv[i] = __expf(q[0]); vv[i + 1] = __expf(q[1]);
                vv[i + 2] = __expf(q[2]); vv[i + 3] = __expf(q[3]);
            }
            float ssum = 0.f;
#pragma unroll
            for (int i = 0; i < 16; i++) { ssum += vv[i]; creg[i] += vv[i]; }
            ssum += __shfl_down(ssum, 4, 8);
            ssum += __shfl_down(ssum, 2, 8);
            ssum += __shfl_down(ssum, 1, 8);
            if (ch == 0) rsum[(size_t)blockIdx.x * 6400 + grow] = ssum;
            uint4 q0 = { cvtpk(vv[0], vv[1]), cvtpk(vv[2], vv[3]),
                         cvtpk(vv[4], vv[5]), cvtpk(vv[6], vv[7]) };
            uint4 q1 = { cvtpk(vv[8], vv[9]), cvtpk(vv[10], vv[11]),
                         cvtpk(vv[12], vv[13]), cvtpk(vv[14], vv[15]) };
            *(uint4*)&Cu[(size_t)grow * ldc + gcol] = q0;
            *(uint4*)&Cu[(size_t)grow * ldc + gcol + 8] = q1;
            if (!diag) {
#pragma unroll
                for (int i = 0; i < 16; i++) lt[lr * 132 + ch * 16 + i] = vv[i];
                __syncthreads();
                const int j = tid >> 1, h = tid & 1;
                ushort mo[16];
#pragma unroll
                for (int i = 0; i < 16; i += 2) {
                    float a = lt[(h * 16 + i) * 132 + j];
                    float b2 = lt[(h * 16 + i + 1) * 132 + j];
                    *(uint32_t*)&mo[i] = cvtpk(a, b2);
                }
                const size_t mbase = (size_t)(bN + j) * ldc + bM + h * 64 + mi * 16;
                *(uint4*)&Cu[mbase] = *(const uint4*)&mo[0];
                *(uint4*)&Cu[mbase + 8] = *(const uint4*)&mo[8];
            }
            __syncthreads();
        }
        if (!diag) {
#pragma unroll
            for (int i = 0; i < 16; i++) lt[lr * 132 + ch * 16 + i] = creg[i];
            __syncthreads();
            if (tid < 128) {
                float s = 0.f;
#pragma unroll
                for (int r = 0; r < 32; r++) s += lt[r * 132 + tid];
                rsum[(size_t)blockIdx.y * 6400 + bN + tid] = s;
            }
        }
        return;
    }

#pragma unroll
    for (int mi = 0; mi < 4; ++mi) {
#pragma unroll
        for (int ni = 0; ni < 4; ++ni) {
            const int lcol = wn * 64 + ni * 16 + cl;
#pragma unroll
            for (int r = 0; r < 4; ++r)
                lt[(wm * 16 + g4 + r) * 132 + lcol] = acc[mi][ni][r];
        }
        __syncthreads();
        {
            const int brow = (lr < 16) ? (mi * 16 + lr) : (64 + mi * 16 + (lr - 16));
            const int grow = bM + brow;
            const int gcol = bN + ch * 16;
            float vv[16];
#pragma unroll
            for (int i = 0; i < 16; i += 4) {
                f32x4 q = *(const f32x4*)&lt[lr * 132 + ch * 16 + i];
                vv[i] = q[0]; vv[i + 1] = q[1]; vv[i + 2] = q[2]; vv[i + 3] = q[3];
            }
            if (EPI == 1) {
#pragma unroll
                for (int i = 0; i < 16; i++)
                    vv[i] = fmaxf(vv[i] * vec0[gcol + i] + vec1[gcol + i], 0.f);
            }
            if (EPI == 2 || EPI == 3) {
                const float rb = vec0[grow];
#pragma unroll
                for (int i = 0; i < 16; i++) vv[i] += rb;
            }
            if (EPI == 3) {
#pragma unroll
                for (int i = 0; i < 16; i += 4) {
                    f32x4 q = { vv[i], vv[i + 1], vv[i + 2], vv[i + 3] };
                    *(f32x4*)&Cf[(size_t)grow * ldc + gcol + i] = q;
                }
            } else {
                uint4 q0 = { cvtpk(vv[0], vv[1]), cvtpk(vv[2], vv[3]),
                             cvtpk(vv[4], vv[5]), cvtpk(vv[6], vv[7]) };
                uint4 q1 = { cvtpk(vv[8], vv[9]), cvtpk(vv[10], vv[11]),
                             cvtpk(vv[12], vv[13]), cvtpk(vv[14], vv[15]) };
                *(uint4*)&Cu[(size_t)grow * ldc + gcol] = q0;
                *(uint4*)&Cu[(size_t)grow * ldc + gcol + 8] = q1;
            }
        }
        __syncthreads();
    }
}

// ---------------- PV GEMM, half-height tile for TLP: 64x128, 4 waves ----------------
// Wave tile 32x64 (acc[2][4]). LDS = 3 bufs x (A 4KB + B 8KB) = 36 KB -> 4
// blocks/CU; grid (2,100,5) = 1000 blocks, all co-resident (~16 waves/CU, 2x
// round-6 PV). Same counted-vmcnt 2-deep pipeline (3 loads/wave/stage ->
// vmcnt(3)) + quarter swizzle. f32 stores (split-K partials).
__global__ __launch_bounds__(256) void gemm_pv64(
    const ushort* __restrict__ A, const ushort* __restrict__ B, float* __restrict__ Cout,
    int K, int lda, int ldb, int ldc,
    size_t zsa, size_t zsb, size_t zsc) {
    // [ A buf0|1|2 : 2048 u each | B buf0|1|2 : 4096 u each ] = 36 KB
    __shared__ __align__(16) ushort smem[3 * 2048 + 3 * 4096];

    A += (size_t)blockIdx.z * zsa;
    B += (size_t)blockIdx.z * zsb;

    const int tid = threadIdx.x;
    const int lane = tid & 63, wave = tid >> 6;
    const int wm = wave & 1, wn = wave >> 1;
    const int bM = blockIdx.y * 64, bN = blockIdx.x * 128;

    const int sr = lane >> 2;
    const int scs = ((lane & 3) ^ ((lane >> 3) & 3)) * 8;
    // A: 64 rows; wave stages rows [wave*16, +16) via one async16
    const ushort* gA0 = A + (size_t)(bM + wave * 16 + sr) * lda + scs;
    // B: 128 rows; wave stages rows [wave*32, +32) via two async16
    const ushort* gB0 = B + (size_t)(bN + wave * 32 + sr) * ldb + scs;
    const ushort* gB1 = gB0 + (size_t)16 * ldb;
    ushort* lAw = &smem[wave * 512];               // + buf*2048
    ushort* lBw = &smem[3 * 2048 + wave * 1024];   // + buf*4096

    const int rowA = wm * 32;
    const int rowB = wn * 64;
    const int fr = lane & 15;
    const int fk = ((lane >> 4) ^ ((fr >> 1) & 3)) * 8;

    f32x4 acc[2][4] = {};
    const int nT = K >> 5;

    auto stage = [&](int t, int buf) {
        const int k0 = t * 32;
        async16(gA0 + k0, lAw + buf * 2048);
        async16(gB0 + k0, lBw + buf * 4096);
        async16(gB1 + k0, lBw + buf * 4096 + 512);
    };

    stage(0, 0);
    if (nT > 1) stage(1, 1);

    for (int t = 0; t < nT; ++t) {
        if (t + 1 < nT) { asm volatile("s_waitcnt vmcnt(3)" ::: "memory"); }
        else            { asm volatile("s_waitcnt vmcnt(0)" ::: "memory"); }
        __builtin_amdgcn_sched_barrier(0);
        __builtin_amdgcn_s_barrier();
        __builtin_amdgcn_sched_barrier(0);
        if (t + 2 < nT) stage(t + 2, (t + 2) % 3);
        const int cur = t % 3;
        const ushort* lA = &smem[cur * 2048];
        const ushort* lB = &smem[3 * 2048 + cur * 4096];
        bf16x8 af[2], bff[4];
#pragma unroll
        for (int mi = 0; mi < 2; mi++)
            af[mi] = *(const bf16x8*)&lA[(rowA + mi * 16 + fr) * 32 + fk];
#pragma unroll
        for (int ni = 0; ni < 4; ni++)
            bff[ni] = *(const bf16x8*)&lB[(rowB + ni * 16 + fr) * 32 + fk];
#pragma unroll
        for (int mi = 0; mi < 2; mi++)
#pragma unroll
            for (int ni = 0; ni < 4; ni++)
                acc[mi][ni] = __builtin_amdgcn_mfma_f32_16x16x32_bf16(af[mi], bff[ni], acc[mi][ni], 0, 0, 0);
        __builtin_amdgcn_sched_barrier(0);
    }
    __builtin_amdgcn_s_barrier();
    __builtin_amdgcn_sched_barrier(0);

    // ---- epilogue: 2 strips through lt[32][132], full-line f32 stores ----
    float* Cf = Cout + (size_t)blockIdx.z * zsc;
    float* lt = (float*)smem;          // 16896 B <= 36864 B
    const int g4 = (lane >> 4) * 4;
    const int cl = fr;
    const int lr = tid >> 3;
    const int ch = tid & 7;

#pragma unroll
    for (int mi = 0; mi < 2; ++mi) {
#pragma unroll
        for (int ni = 0; ni < 4; ++ni) {
            const int lcol = wn * 64 + ni * 16 + cl;
#pragma unroll
            for (int r = 0; r < 4; ++r)
                lt[(wm * 16 + g4 + r) * 132 + lcol] = acc[mi][ni][r];
        }
        __syncthreads();
        {
            const int brow = (lr < 16) ? (mi * 16 + lr) : (32 + mi * 16 + (lr - 16));
            const int grow = bM + brow;
            const int gcol = bN + ch * 16;
#pragma unroll
            for (int i = 0; i < 16; i += 4) {
                f32x4 q = *(const f32x4*)&lt[lr * 132 + ch * 16 + i];
                *(f32x4*)&Cf[(size_t)grow * ldc + gcol + i] = q;
            }
        }
        __syncthreads();
    }
}

// ---------------- softmax normalizer: inv[row] = 1 / sum_xb rsum[xb][row] ----------------
__global__ __launch_bounds__(256) void combine_inv(const float* __restrict__ rsum,
                                                   float* __restrict__ inv) {
    int r = blockIdx.x * 256 + threadIdx.x;   // 6400 rows
    float s = 0.f;
#pragma unroll
    for (int xb = 0; xb < 50; xb++) s += rsum[(size_t)xb * 6400 + r];
    inv[r] = 1.f / s;
}

// ---------------- split-K reduce: ctxT bf16 = inv[row] * sum of 5 f32 partial chunks ----------------
__global__ __launch_bounds__(256) void reduce_ctx(const float* __restrict__ part, ushort* __restrict__ ctx,
                                                  const float* __restrict__ inv) {
    const size_t CH = 1638400;  // elems per chunk
    size_t i = ((size_t)blockIdx.x * 256 + threadIdx.x) * 4;
    float4 a = *(const float4*)&part[i];
#pragma unroll
    for (int c = 1; c < 5; c++) {
        float4 s = *(const float4*)&part[i + (size_t)c * CH];
        a.x += s.x; a.y += s.y; a.z += s.z; a.w += s.w;
    }
    const float w = inv[i >> 8];  // 256 cols per row; 4 consecutive elems share a row
    uint2 o = { cvtpk(a.x * w, a.y * w), cvtpk(a.z * w, a.w * w) };
    *(uint2*)&ctx[i] = o;
}

// ---------------- host ----------------
extern "C" void kernel_launch(void* const* d_in, const int* in_sizes, int n_in,
                              void* d_out, int out_size, void* d_ws, size_t ws_size,
                              hipStream_t stream) {
    (void)in_sizes; (void)n_in; (void)out_size; (void)ws_size;
    const float* x     = (const float*)d_in[0];
    const float* wk    = (const float*)d_in[1];
    const float* bk    = (const float*)d_in[2];
    const float* gamma = (const float*)d_in[3];
    const float* beta  = (const float*)d_in[4];
    const float* rmean = (const float*)d_in[5];
    const float* rvar  = (const float*)d_in[6];
    const float* wv    = (const float*)d_in[7];
    const float* bv    = (const float*)d_in[8];
    const float* wW    = (const float*)d_in[9];
    const float* bW    = (const float*)d_in[10];
    float* out = (float*)d_out;

    // workspace layout (ushort elements)
    ushort* Xt   = (ushort*)d_ws;          // 2*6400*512   = 6,553,600
    ushort* wkb  = Xt + 6553600;           // 256*512      = 131,072
    ushort* wvb  = wkb + 131072;           // 131,072
    ushort* wWb  = wvb + 131072;           // 131,072
    ushort* Kt   = wWb + 131072;           // 2*6400*256   = 3,276,800
    ushort* V    = Kt + 3276800;           // 3,276,800
    ushort* ctxT = V + 3276800;            // 3,276,800
    ushort* S    = ctxT + 3276800;         // 6400*6400    = 40,960,000 (one batch, reused)
    float* scaleA = (float*)(S + 40960000);
    float* shiftA = scaleA + 256;
    float* rowsum = shiftA + 256;          // 50*6400      = 320,000 f32
    float* inv    = rowsum + 320000;       // 6400 f32
    float* part   = inv + 6400;            // 5*6400*256 f32 = 8,192,000 f32 (33 MB)
    // total ~150 MB

    cvt_f32_bf16<<<512, 256, 0, stream>>>(wk, wkb, 131072);
    cvt_f32_bf16<<<512, 256, 0, stream>>>(wv, wvb, 131072);
    cvt_f32_bf16<<<512, 256, 0, stream>>>(wW, wWb, 131072);
    prep_bn<<<1, 256, 0, stream>>>(bk, gamma, beta, rmean, rvar, scaleA, shiftA);
    transpose_cvt<<<dim3(200, 16, 2), dim3(32, 32), 0, stream>>>(x, Xt);

    // Kt[b][n][ck] = relu(affine(Xt . wk^T)), scaled by 0.25  — both batches in one dispatch
    gemm_nt<1><<<dim3(2, 50, 2), 256, 0, stream>>>(Xt, wkb, Kt, 512, 512, 512, 256,
                                                   3276800, 0, 1638400, scaleA, shiftA, nullptr);
    // V[b][v][m] = wv . Xt^T + bv
    gemm_nt<2><<<dim3(50, 2, 2), 256, 0, stream>>>(wvb, Xt, V, 512, 512, 512, 6400,
                                                   0, 3276800, 1638400, bv, nullptr, nullptr);

    for (int b = 0; b < 2; b++) {
        ushort* Ktb  = Kt + (size_t)b * 1638400;
        ushort* Vb   = V  + (size_t)b * 1638400;
        ushort* ctxb = ctxT + (size_t)b * 1638400;
        // P_unnorm = exp(Kt . Kt^T), SYMMETRIC: upper-triangle blocks only,
        // mirrored stores + dual rowsum partials
        gemm_nt<6><<<dim3(50, 50), 256, 0, stream>>>(Ktb, Ktb, S, 256, 256, 256, 6400,
                                                     0, 0, 0, nullptr, nullptr, rowsum);
        combine_inv<<<25, 256, 0, stream>>>(rowsum, inv);
        // ctxT[n][v] = P_unnorm . V^T — split-K x5, 64x128 tiles (1000 blocks, 4/CU)
        gemm_pv64<<<dim3(2, 100, 5), 256, 0, stream>>>(S, Vb, part, 1280, 6400, 6400, 256,
                                                       1280, 1280, 1638400);
        reduce_ctx<<<1600, 256, 0, stream>>>(part, ctxb, inv);
    }

    // out[b][o][n] = wW . ctxT^T + bW  — both batches in one dispatch
    gemm_nt<3><<<dim3(50, 4, 2), 256, 0, stream>>>(wWb, ctxT, out, 256, 256, 256, 6400,
                                                   0, 1638400, 3276800, bW, nullptr, nullptr);
}

// Round 13
// 305.587 us; speedup vs baseline: 1.0749x; 1.0749x over previous
//
#include <hip/hip_runtime.h>
#include <stdint.h>

typedef __attribute__((ext_vector_type(8))) short bf16x8;
typedef __attribute__((ext_vector_type(4))) float f32x4;

__device__ __forceinline__ ushort f2bf(float f) {
    union { float f; uint32_t i; } v; v.f = f;
    uint32_t r = v.i + 0x7fff + ((v.i >> 16) & 1);
    return (ushort)(r >> 16);
}
__device__ __forceinline__ uint32_t cvtpk(float lo, float hi) {
    uint32_t r;
    asm("v_cvt_pk_bf16_f32 %0, %1, %2" : "=v"(r) : "v"(lo), "v"(hi));
    return r;
}

typedef unsigned int uint_as1 __attribute__((address_space(1)));
typedef unsigned int uint_as3 __attribute__((address_space(3)));
__device__ __forceinline__ void async16(const void* g, void* l) {
    __builtin_amdgcn_global_load_lds((const uint_as1*)g, (uint_as3*)l, 16, 0, 0);
}

// ---------------- merged prep: weight cvt x3 + BN fold (one dispatch) ----------------
__global__ void prep_all(const float* __restrict__ wk, const float* __restrict__ wv,
                         const float* __restrict__ wW,
                         const float* __restrict__ bk, const float* __restrict__ gamma,
                         const float* __restrict__ beta, const float* __restrict__ rmean,
                         const float* __restrict__ rvar,
                         ushort* __restrict__ wkb, ushort* __restrict__ wvb,
                         ushort* __restrict__ wWb,
                         float* __restrict__ scaleA, float* __restrict__ shiftA) {
    const int b = blockIdx.x;
    if (b == 1536) {
        int i = threadIdx.x;   // 256 threads
        float s = gamma[i] * rsqrtf(rvar[i] + 1e-5f);
        scaleA[i] = 0.25f * s;                                // fold Ck^-0.5 = 1/16 as 0.25 per operand
        shiftA[i] = 0.25f * ((bk[i] - rmean[i]) * s + beta[i]);
        return;
    }
    const int i = (b & 511) * 256 + threadIdx.x;   // 512 blocks x 256 = 131072 per tensor
    const float* src = (b < 512) ? wk : (b < 1024) ? wv : wW;
    ushort* dst = (b < 512) ? wkb : (b < 1024) ? wvb : wWb;
    dst[i] = f2bf(src[i]);
}

// x [b][512][6400] f32  ->  Xt [b][6400][512] bf16
__global__ void transpose_cvt(const float* __restrict__ x, ushort* __restrict__ xt) {
    __shared__ float t[32][33];
    int b = blockIdx.z;
    int n0 = blockIdx.x * 32, c0 = blockIdx.y * 32;
    const float* xb = x + (size_t)b * 512 * 6400;
    ushort* xtb = xt + (size_t)b * 6400 * 512;
    int tx = threadIdx.x, ty = threadIdx.y;
    t[ty][tx] = xb[(size_t)(c0 + ty) * 6400 + n0 + tx];
    __syncthreads();
    xtb[(size_t)(n0 + ty) * 512 + c0 + tx] = f2bf(t[tx][ty]);
}

// ---------------- unified NT GEMM: C[i][j] = sum_k A[i][k]*B[j][k] ----------------
// Round-6 proven core: 128x128 tile, 4 waves, BK=32, 3-buf LDS, counted vmcnt(4)
// + raw s_barrier per K-step. LDS quarter-swizzle (SQ_LDS_BANK_CONFLICT = 0).
// Epilogue repacks acc through LDS for full-line stores; bf16 via v_cvt_pk_bf16_f32.
// EPI 1: bf16 store relu(acc*vec0[col] + vec1[col])   (col-affine, BN+ReLU for Kt)
// EPI 2: bf16 store acc + vec0[row]                   (row bias, V)
// EPI 3: f32  store acc + vec0[row]                   (row bias, final out)
// EPI 4: f32  store raw                               (split-K partials, PV)
// EPI 6: SYMMETRIC exp tile (round-11 validated): bx >= by only; store exp(acc)
//        tile AND mirror; rsum[bx][rows] / rsum[by][cols] partials.
template <int EPI>
__global__ __launch_bounds__(256) void gemm_nt(
    const ushort* __restrict__ A, const ushort* __restrict__ B, void* __restrict__ Cout,
    int K, int lda, int ldb, int ldc,
    size_t zsa, size_t zsb, size_t zsc,
    const float* __restrict__ vec0, const float* __restrict__ vec1,
    float* __restrict__ rsum) {
    if (EPI == 6 && blockIdx.x < blockIdx.y) return;   // lower triangle: no-op

    __shared__ __align__(16) ushort smem[6 * 4096];

    A += (size_t)blockIdx.z * zsa;
    B += (size_t)blockIdx.z * zsb;

    const int tid = threadIdx.x;
    const int lane = tid & 63, wave = tid >> 6;
    const int wm = wave & 1, wn = wave >> 1;
    const int bM = blockIdx.y * 128, bN = blockIdx.x * 128;

    const int sr = lane >> 2;
    const int scs = ((lane & 3) ^ ((lane >> 3) & 3)) * 8;
    const ushort* gA0 = A + (size_t)(bM + wave * 32 + sr) * lda + scs;
    const ushort* gA1 = gA0 + (size_t)16 * lda;
    const ushort* gB0 = B + (size_t)(bN + wave * 32 + sr) * ldb + scs;
    const ushort* gB1 = gB0 + (size_t)16 * ldb;
    ushort* lAw = &smem[wave * 1024];
    ushort* lBw = &smem[3 * 4096 + wave * 1024];

    const int rowA = wm * 64;
    const int rowB = wn * 64;
    const int fr = lane & 15;
    const int fk = ((lane >> 4) ^ ((fr >> 1) & 3)) * 8;

    f32x4 acc[4][4] = {};
    const int nT = K >> 5;

    auto stage = [&](int t, int buf) {
        const int k0 = t * 32;
        const int ob = buf * 4096;
        async16(gA0 + k0, lAw + ob);
        async16(gA1 + k0, lAw + ob + 512);
        async16(gB0 + k0, lBw + ob);
        async16(gB1 + k0, lBw + ob + 512);
    };

    stage(0, 0);
    if (nT > 1) stage(1, 1);

    for (int t = 0; t < nT; ++t) {
        if (t + 1 < nT) { asm volatile("s_waitcnt vmcnt(4)" ::: "memory"); }
        else            { asm volatile("s_waitcnt vmcnt(0)" ::: "memory"); }
        __builtin_amdgcn_sched_barrier(0);
        __builtin_amdgcn_s_barrier();
        __builtin_amdgcn_sched_barrier(0);
        if (t + 2 < nT) stage(t + 2, (t + 2) % 3);
        const int cur = t % 3;
        const ushort* lA = &smem[cur * 4096];
        const ushort* lB = &smem[3 * 4096 + cur * 4096];
        bf16x8 af[4], bff[4];
#pragma unroll
        for (int mi = 0; mi < 4; mi++)
            af[mi] = *(const bf16x8*)&lA[(rowA + mi * 16 + fr) * 32 + fk];
#pragma unroll
        for (int ni = 0; ni < 4; ni++)
            bff[ni] = *(const bf16x8*)&lB[(rowB + ni * 16 + fr) * 32 + fk];
#pragma unroll
        for (int mi = 0; mi < 4; mi++)
#pragma unroll
            for (int ni = 0; ni < 4; ni++)
                acc[mi][ni] = __builtin_amdgcn_mfma_f32_16x16x32_bf16(af[mi], bff[ni], acc[mi][ni], 0, 0, 0);
        __builtin_amdgcn_sched_barrier(0);
    }
    __builtin_amdgcn_s_barrier();
    __builtin_amdgcn_sched_barrier(0);

    // ---- epilogue: repack through LDS, store full lines ----
    float* Cf = (float*)Cout + (size_t)blockIdx.z * zsc;
    ushort* Cu = (ushort*)Cout + (size_t)blockIdx.z * zsc;
    float* lt = (float*)smem;
    const int g4 = (lane >> 4) * 4;
    const int cl = lane & 15;
    const int lr = tid >> 3;
    const int ch = tid & 7;

    if (EPI == 6) {
        const bool diag = (blockIdx.x == blockIdx.y);
        float creg[16];
#pragma unroll
        for (int i = 0; i < 16; i++) creg[i] = 0.f;
#pragma unroll
        for (int mi = 0; mi < 4; ++mi) {
#pragma unroll
            for (int ni = 0; ni < 4; ++ni) {
                const int lcol = wn * 64 + ni * 16 + cl;
#pragma unroll
                for (int r = 0; r < 4; ++r)
                    lt[(wm * 16 + g4 + r) * 132 + lcol] = acc[mi][ni][r];
            }
            __syncthreads();
            const int brow = (lr < 16) ? (mi * 16 + lr) : (64 + mi * 16 + (lr - 16));
            const int grow = bM + brow;
            const int gcol = bN + ch * 16;
            float vv[16];
#pragma unroll
            for (int i = 0; i < 16; i += 4) {
                f32x4 q = *(const f32x4*)&lt[lr * 132 + ch * 16 + i];
                vv[i] = __expf(q[0]); vv[i + 1] = __expf(q[1]);
                vv[i + 2] = __expf(q[2]); vv[i + 3] = __expf(q[3]);
            }
            float ssum = 0.f;
#pragma unroll
            for (int i = 0; i < 16; i++) { ssum += vv[i]; creg[i] += vv[i]; }
            ssum += __shfl_down(ssum, 4, 8);
            ssum += __shfl_down(ssum, 2, 8);
            ssum += __shfl_down(ssum, 1, 8);
            if (ch == 0) rsum[(size_t)blockIdx.x * 6400 + grow] = ssum;
            uint4 q0 = { cvtpk(vv[0], vv[1]), cvtpk(vv[2], vv[3]),
                         cvtpk(vv[4], vv[5]), cvtpk(vv[6], vv[7]) };
            uint4 q1 = { cvtpk(vv[8], vv[9]), cvtpk(vv[10], vv[11]),
                         cvtpk(vv[12], vv[13]), cvtpk(vv[14], vv[15]) };
            *(uint4*)&Cu[(size_t)grow * ldc + gcol] = q0;
            *(uint4*)&Cu[(size_t)grow * ldc + gcol + 8] = q1;
            if (!diag) {
#pragma unroll
                for (int i = 0; i < 16; i++) lt[lr * 132 + ch * 16 + i] = vv[i];
                __syncthreads();
                const int j = tid >> 1, h = tid & 1;
                ushort mo[16];
#pragma unroll
                for (int i = 0; i < 16; i += 2) {
                    float a = lt[(h * 16 + i) * 132 + j];
                    float b2 = lt[(h * 16 + i + 1) * 132 + j];
                    *(uint32_t*)&mo[i] = cvtpk(a, b2);
                }
                const size_t mbase = (size_t)(bN + j) * ldc + bM + h * 64 + mi * 16;
                *(uint4*)&Cu[mbase] = *(const uint4*)&mo[0];
                *(uint4*)&Cu[mbase + 8] = *(const uint4*)&mo[8];
            }
            __syncthreads();
        }
        if (!diag) {
#pragma unroll
            for (int i = 0; i < 16; i++) lt[lr * 132 + ch * 16 + i] = creg[i];
            __syncthreads();
            if (tid < 128) {
                float s = 0.f;
#pragma unroll
                for (int r = 0; r < 32; r++) s += lt[r * 132 + tid];
                rsum[(size_t)blockIdx.y * 6400 + bN + tid] = s;
            }
        }
        return;
    }

#pragma unroll
    for (int mi = 0; mi < 4; ++mi) {
#pragma unroll
        for (int ni = 0; ni < 4; ++ni) {
            const int lcol = wn * 64 + ni * 16 + cl;
#pragma unroll
            for (int r = 0; r < 4; ++r)
                lt[(wm * 16 + g4 + r) * 132 + lcol] = acc[mi][ni][r];
        }
        __syncthreads();
        {
            const int brow = (lr < 16) ? (mi * 16 + lr) : (64 + mi * 16 + (lr - 16));
            const int grow = bM + brow;
            const int gcol = bN + ch * 16;
            float vv[16];
#pragma unroll
            for (int i = 0; i < 16; i += 4) {
                f32x4 q = *(const f32x4*)&lt[lr * 132 + ch * 16 + i];
                vv[i] = q[0]; vv[i + 1] = q[1]; vv[i + 2] = q[2]; vv[i + 3] = q[3];
            }
            if (EPI == 1) {
#pragma unroll
                for (int i = 0; i < 16; i++)
                    vv[i] = fmaxf(vv[i] * vec0[gcol + i] + vec1[gcol + i], 0.f);
            }
            if (EPI == 2 || EPI == 3) {
                const float rb = vec0[grow];
#pragma unroll
                for (int i = 0; i < 16; i++) vv[i] += rb;
            }
            if (EPI == 3 || EPI == 4) {
#pragma unroll
                for (int i = 0; i < 16; i += 4) {
                    f32x4 q = { vv[i], vv[i + 1], vv[i + 2], vv[i + 3] };
                    *(f32x4*)&Cf[(size_t)grow * ldc + gcol + i] = q;
                }
            } else {
                uint4 q0 = { cvtpk(vv[0], vv[1]), cvtpk(vv[2], vv[3]),
                             cvtpk(vv[4], vv[5]), cvtpk(vv[6], vv[7]) };
                uint4 q1 = { cvtpk(vv[8], vv[9]), cvtpk(vv[10], vv[11]),
                             cvtpk(vv[12], vv[13]), cvtpk(vv[14], vv[15]) };
                *(uint4*)&Cu[(size_t)grow * ldc + gcol] = q0;
                *(uint4*)&Cu[(size_t)grow * ldc + gcol + 8] = q1;
            }
        }
        __syncthreads();
    }
}

// ---------------- split-K reduce + inline softmax normalizer ----------------
// ctxT bf16 = (1/sum_xb rsum[xb][row]) * sum of 5 f32 partial chunks.
// rsum is 1.28 MB (L2-hot); per-thread 50-way sum replaces the combine_inv
// dispatch (saves 2 launches).
__global__ __launch_bounds__(256) void reduce_ctx(const float* __restrict__ part, ushort* __restrict__ ctx,
                                                  const float* __restrict__ rsum) {
    const size_t CH = 1638400;  // elems per chunk
    size_t i = ((size_t)blockIdx.x * 256 + threadIdx.x) * 4;
    float4 a = *(const float4*)&part[i];
#pragma unroll
    for (int c = 1; c < 5; c++) {
        float4 s = *(const float4*)&part[i + (size_t)c * CH];
        a.x += s.x; a.y += s.y; a.z += s.z; a.w += s.w;
    }
    const int row = (int)(i >> 8);  // 256 cols per row; 4 consecutive elems share a row
    float s = 0.f;
#pragma unroll
    for (int xb = 0; xb < 50; xb++) s += rsum[(size_t)xb * 6400 + row];
    const float w = 1.f / s;
    uint2 o = { cvtpk(a.x * w, a.y * w), cvtpk(a.z * w, a.w * w) };
    *(uint2*)&ctx[i] = o;
}

// ---------------- host ----------------
extern "C" void kernel_launch(void* const* d_in, const int* in_sizes, int n_in,
                              void* d_out, int out_size, void* d_ws, size_t ws_size,
                              hipStream_t stream) {
    (void)in_sizes; (void)n_in; (void)out_size; (void)ws_size;
    const float* x     = (const float*)d_in[0];
    const float* wk    = (const float*)d_in[1];
    const float* bk    = (const float*)d_in[2];
    const float* gamma = (const float*)d_in[3];
    const float* beta  = (const float*)d_in[4];
    const float* rmean = (const float*)d_in[5];
    const float* rvar  = (const float*)d_in[6];
    const float* wv    = (const float*)d_in[7];
    const float* bv    = (const float*)d_in[8];
    const float* wW    = (const float*)d_in[9];
    const float* bW    = (const float*)d_in[10];
    float* out = (float*)d_out;

    // workspace layout (ushort elements)
    ushort* Xt   = (ushort*)d_ws;          // 2*6400*512   = 6,553,600
    ushort* wkb  = Xt + 6553600;           // 256*512      = 131,072
    ushort* wvb  = wkb + 131072;           // 131,072
    ushort* wWb  = wvb + 131072;           // 131,072
    ushort* Kt   = wWb + 131072;           // 2*6400*256   = 3,276,800
    ushort* V    = Kt + 3276800;           // 3,276,800
    ushort* ctxT = V + 3276800;            // 3,276,800
    ushort* S    = ctxT + 3276800;         // 6400*6400    = 40,960,000 (one batch, reused)
    float* scaleA = (float*)(S + 40960000);
    float* shiftA = scaleA + 256;
    float* rowsum = shiftA + 256;          // 50*6400      = 320,000 f32
    float* part   = rowsum + 320000;       // 5*6400*256 f32 = 8,192,000 f32 (33 MB)
    // total ~150 MB

    prep_all<<<1537, 256, 0, stream>>>(wk, wv, wW, bk, gamma, beta, rmean, rvar,
                                       wkb, wvb, wWb, scaleA, shiftA);
    transpose_cvt<<<dim3(200, 16, 2), dim3(32, 32), 0, stream>>>(x, Xt);

    // Kt[b][n][ck] = relu(affine(Xt . wk^T)), scaled by 0.25  — both batches in one dispatch
    gemm_nt<1><<<dim3(2, 50, 2), 256, 0, stream>>>(Xt, wkb, Kt, 512, 512, 512, 256,
                                                   3276800, 0, 1638400, scaleA, shiftA, nullptr);
    // V[b][v][m] = wv . Xt^T + bv
    gemm_nt<2><<<dim3(50, 2, 2), 256, 0, stream>>>(wvb, Xt, V, 512, 512, 512, 6400,
                                                   0, 3276800, 1638400, bv, nullptr, nullptr);

    for (int b = 0; b < 2; b++) {
        ushort* Ktb  = Kt + (size_t)b * 1638400;
        ushort* Vb   = V  + (size_t)b * 1638400;
        ushort* ctxb = ctxT + (size_t)b * 1638400;
        // P_unnorm = exp(Kt . Kt^T), SYMMETRIC: upper-triangle blocks only,
        // mirrored stores + dual rowsum partials
        gemm_nt<6><<<dim3(50, 50), 256, 0, stream>>>(Ktb, Ktb, S, 256, 256, 256, 6400,
                                                     0, 0, 0, nullptr, nullptr, rowsum);
        // ctxT[n][v] = P_unnorm . V^T — split-K x5 into f32 partials (z = k-chunk of 1280)
        gemm_nt<4><<<dim3(2, 50, 5), 256, 0, stream>>>(S, Vb, part, 1280, 6400, 6400, 256,
                                                       1280, 1280, 1638400, nullptr, nullptr, nullptr);
        reduce_ctx<<<1600, 256, 0, stream>>>(part, ctxb, rowsum);
    }

    // out[b][o][n] = wW . ctxT^T + bW  — both batches in one dispatch
    gemm_nt<3><<<dim3(50, 4, 2), 256, 0, stream>>>(wWb, ctxT, out, 256, 256, 256, 6400,
                                                   0, 1638400, 3276800, bW, nullptr, nullptr);
}

// Round 14
// 297.414 us; speedup vs baseline: 1.1044x; 1.0275x over previous
//
#include <hip/hip_runtime.h>
#include <stdint.h>

typedef __attribute__((ext_vector_type(8))) short bf16x8;
typedef __attribute__((ext_vector_type(4))) float f32x4;

__device__ __forceinline__ ushort f2bf(float f) {
    union { float f; uint32_t i; } v; v.f = f;
    uint32_t r = v.i + 0x7fff + ((v.i >> 16) & 1);
    return (ushort)(r >> 16);
}
__device__ __forceinline__ uint32_t cvtpk(float lo, float hi) {
    uint32_t r;
    asm("v_cvt_pk_bf16_f32 %0, %1, %2" : "=v"(r) : "v"(lo), "v"(hi));
    return r;
}

typedef unsigned int uint_as1 __attribute__((address_space(1)));
typedef unsigned int uint_as3 __attribute__((address_space(3)));
__device__ __forceinline__ void async16(const void* g, void* l) {
    __builtin_amdgcn_global_load_lds((const uint_as1*)g, (uint_as3*)l, 16, 0, 0);
}

// ---------------- merged prep: weight cvt x3 + BN fold (one dispatch) ----------------
__global__ void prep_all(const float* __restrict__ wk, const float* __restrict__ wv,
                         const float* __restrict__ wW,
                         const float* __restrict__ bk, const float* __restrict__ gamma,
                         const float* __restrict__ beta, const float* __restrict__ rmean,
                         const float* __restrict__ rvar,
                         ushort* __restrict__ wkb, ushort* __restrict__ wvb,
                         ushort* __restrict__ wWb,
                         float* __restrict__ scaleA, float* __restrict__ shiftA) {
    const int b = blockIdx.x;
    if (b == 1536) {
        int i = threadIdx.x;   // 256 threads
        float s = gamma[i] * rsqrtf(rvar[i] + 1e-5f);
        scaleA[i] = 0.25f * s;                                // fold Ck^-0.5 = 1/16 as 0.25 per operand
        shiftA[i] = 0.25f * ((bk[i] - rmean[i]) * s + beta[i]);
        return;
    }
    const int i = (b & 511) * 256 + threadIdx.x;   // 512 blocks x 256 = 131072 per tensor
    const float* src = (b < 512) ? wk : (b < 1024) ? wv : wW;
    ushort* dst = (b < 512) ? wkb : (b < 1024) ? wvb : wWb;
    dst[i] = f2bf(src[i]);
}

// x [b][512][6400] f32  ->  Xt [b][6400][512] bf16
__global__ void transpose_cvt(const float* __restrict__ x, ushort* __restrict__ xt) {
    __shared__ float t[32][33];
    int b = blockIdx.z;
    int n0 = blockIdx.x * 32, c0 = blockIdx.y * 32;
    const float* xb = x + (size_t)b * 512 * 6400;
    ushort* xtb = xt + (size_t)b * 6400 * 512;
    int tx = threadIdx.x, ty = threadIdx.y;
    t[ty][tx] = xb[(size_t)(c0 + ty) * 6400 + n0 + tx];
    __syncthreads();
    xtb[(size_t)(n0 + ty) * 512 + c0 + tx] = f2bf(t[tx][ty]);
}

// ---------------- unified NT GEMM body: C[i][j] = sum_k A[i][k]*B[j][k] ----------------
// Round-6 proven core: 128x128 tile, 4 waves, BK=32, 3-buf LDS, counted vmcnt(4)
// + raw s_barrier per K-step. LDS quarter-swizzle (SQ_LDS_BANK_CONFLICT = 0).
// Epilogue repacks acc through LDS for full-line stores; bf16 via v_cvt_pk_bf16_f32.
// EPI 1: bf16 store relu(acc*vec0[col] + vec1[col])   (col-affine, BN+ReLU for Kt)
// EPI 2: bf16 store acc + vec0[row]                   (row bias, V)
// EPI 3: f32  store acc + vec0[row]                   (row bias, final out)
// EPI 4: f32  store raw                               (split-K partials, PV)
// EPI 6: SYMMETRIC exp tile (round-11 validated): bx >= by only (caller filters);
//        store exp(acc) tile AND mirror; rsum[bx][rows] / rsum[by][cols] partials.
template <int EPI>
__device__ __forceinline__ void gemm_body(
    int bxi, int byi, int bzi,
    const ushort* __restrict__ A, const ushort* __restrict__ B, void* __restrict__ Cout,
    int K, int lda, int ldb, int ldc,
    size_t zsa, size_t zsb, size_t zsc,
    const float* __restrict__ vec0, const float* __restrict__ vec1,
    float* __restrict__ rsum, ushort* smem) {

    A += (size_t)bzi * zsa;
    B += (size_t)bzi * zsb;

    const int tid = threadIdx.x;
    const int lane = tid & 63, wave = tid >> 6;
    const int wm = wave & 1, wn = wave >> 1;
    const int bM = byi * 128, bN = bxi * 128;

    const int sr = lane >> 2;
    const int scs = ((lane & 3) ^ ((lane >> 3) & 3)) * 8;
    const ushort* gA0 = A + (size_t)(bM + wave * 32 + sr) * lda + scs;
    const ushort* gA1 = gA0 + (size_t)16 * lda;
    const ushort* gB0 = B + (size_t)(bN + wave * 32 + sr) * ldb + scs;
    const ushort* gB1 = gB0 + (size_t)16 * ldb;
    ushort* lAw = &smem[wave * 1024];
    ushort* lBw = &smem[3 * 4096 + wave * 1024];

    const int rowA = wm * 64;
    const int rowB = wn * 64;
    const int fr = lane & 15;
    const int fk = ((lane >> 4) ^ ((fr >> 1) & 3)) * 8;

    f32x4 acc[4][4] = {};
    const int nT = K >> 5;

    auto stage = [&](int t, int buf) {
        const int k0 = t * 32;
        const int ob = buf * 4096;
        async16(gA0 + k0, lAw + ob);
        async16(gA1 + k0, lAw + ob + 512);
        async16(gB0 + k0, lBw + ob);
        async16(gB1 + k0, lBw + ob + 512);
    };

    stage(0, 0);
    if (nT > 1) stage(1, 1);

    for (int t = 0; t < nT; ++t) {
        if (t + 1 < nT) { asm volatile("s_waitcnt vmcnt(4)" ::: "memory"); }
        else            { asm volatile("s_waitcnt vmcnt(0)" ::: "memory"); }
        __builtin_amdgcn_sched_barrier(0);
        __builtin_amdgcn_s_barrier();
        __builtin_amdgcn_sched_barrier(0);
        if (t + 2 < nT) stage(t + 2, (t + 2) % 3);
        const int cur = t % 3;
        const ushort* lA = &smem[cur * 4096];
        const ushort* lB = &smem[3 * 4096 + cur * 4096];
        bf16x8 af[4], bff[4];
#pragma unroll
        for (int mi = 0; mi < 4; mi++)
            af[mi] = *(const bf16x8*)&lA[(rowA + mi * 16 + fr) * 32 + fk];
#pragma unroll
        for (int ni = 0; ni < 4; ni++)
            bff[ni] = *(const bf16x8*)&lB[(rowB + ni * 16 + fr) * 32 + fk];
#pragma unroll
        for (int mi = 0; mi < 4; mi++)
#pragma unroll
            for (int ni = 0; ni < 4; ni++)
                acc[mi][ni] = __builtin_amdgcn_mfma_f32_16x16x32_bf16(af[mi], bff[ni], acc[mi][ni], 0, 0, 0);
        __builtin_amdgcn_sched_barrier(0);
    }
    __builtin_amdgcn_s_barrier();
    __builtin_amdgcn_sched_barrier(0);

    // ---- epilogue: repack through LDS, store full lines ----
    float* Cf = (float*)Cout + (size_t)bzi * zsc;
    ushort* Cu = (ushort*)Cout + (size_t)bzi * zsc;
    float* lt = (float*)smem;
    const int g4 = (lane >> 4) * 4;
    const int cl = lane & 15;
    const int lr = tid >> 3;
    const int ch = tid & 7;

    if (EPI == 6) {
        const bool diag = (bxi == byi);
        float creg[16];
#pragma unroll
        for (int i = 0; i < 16; i++) creg[i] = 0.f;
#pragma unroll
        for (int mi = 0; mi < 4; ++mi) {
#pragma unroll
            for (int ni = 0; ni < 4; ++ni) {
                const int lcol = wn * 64 + ni * 16 + cl;
#pragma unroll
                for (int r = 0; r < 4; ++r)
                    lt[(wm * 16 + g4 + r) * 132 + lcol] = acc[mi][ni][r];
            }
            __syncthreads();
            const int brow = (lr < 16) ? (mi * 16 + lr) : (64 + mi * 16 + (lr - 16));
            const int grow = bM + brow;
            const int gcol = bN + ch * 16;
            float vv[16];
#pragma unroll
            for (int i = 0; i < 16; i += 4) {
                f32x4 q = *(const f32x4*)&lt[lr * 132 + ch * 16 + i];
                vv[i] = __expf(q[0]); vv[i + 1] = __expf(q[1]);
                vv[i + 2] = __expf(q[2]); vv[i + 3] = __expf(q[3]);
            }
            float ssum = 0.f;
#pragma unroll
            for (int i = 0; i < 16; i++) { ssum += vv[i]; creg[i] += vv[i]; }
            ssum += __shfl_down(ssum, 4, 8);
            ssum += __shfl_down(ssum, 2, 8);
            ssum += __shfl_down(ssum, 1, 8);
            if (ch == 0) rsum[(size_t)bxi * 6400 + grow] = ssum;
            uint4 q0 = { cvtpk(vv[0], vv[1]), cvtpk(vv[2], vv[3]),
                         cvtpk(vv[4], vv[5]), cvtpk(vv[6], vv[7]) };
            uint4 q1 = { cvtpk(vv[8], vv[9]), cvtpk(vv[10], vv[11]),
                         cvtpk(vv[12], vv[13]), cvtpk(vv[14], vv[15]) };
            *(uint4*)&Cu[(size_t)grow * ldc + gcol] = q0;
            *(uint4*)&Cu[(size_t)grow * ldc + gcol + 8] = q1;
            if (!diag) {
#pragma unroll
                for (int i = 0; i < 16; i++) lt[lr * 132 + ch * 16 + i] = vv[i];
                __syncthreads();
                const int j = tid >> 1, h = tid & 1;
                ushort mo[16];
#pragma unroll
                for (int i = 0; i < 16; i += 2) {
                    float a = lt[(h * 16 + i) * 132 + j];
                    float b2 = lt[(h * 16 + i + 1) * 132 + j];
                    *(uint32_t*)&mo[i] = cvtpk(a, b2);
                }
                const size_t mbase = (size_t)(bN + j) * ldc + bM + h * 64 + mi * 16;
                *(uint4*)&Cu[mbase] = *(const uint4*)&mo[0];
                *(uint4*)&Cu[mbase + 8] = *(const uint4*)&mo[8];
            }
            __syncthreads();
        }
        if (!diag) {
#pragma unroll
            for (int i = 0; i < 16; i++) lt[lr * 132 + ch * 16 + i] = creg[i];
            __syncthreads();
            if (tid < 128) {
                float s = 0.f;
#pragma unroll
                for (int r = 0; r < 32; r++) s += lt[r * 132 + tid];
                rsum[(size_t)byi * 6400 + bN + tid] = s;
            }
        }
        return;
    }

#pragma unroll
    for (int mi = 0; mi < 4; ++mi) {
#pragma unroll
        for (int ni = 0; ni < 4; ++ni) {
            const int lcol = wn * 64 + ni * 16 + cl;
#pragma unroll
            for (int r = 0; r < 4; ++r)
                lt[(wm * 16 + g4 + r) * 132 + lcol] = acc[mi][ni][r];
        }
        __syncthreads();
        {
            const int brow = (lr < 16) ? (mi * 16 + lr) : (64 + mi * 16 + (lr - 16));
            const int grow = bM + brow;
            const int gcol = bN + ch * 16;
            float vv[16];
#pragma unroll
            for (int i = 0; i < 16; i += 4) {
                f32x4 q = *(const f32x4*)&lt[lr * 132 + ch * 16 + i];
                vv[i] = q[0]; vv[i + 1] = q[1]; vv[i + 2] = q[2]; vv[i + 3] = q[3];
            }
            if (EPI == 1) {
#pragma unroll
                for (int i = 0; i < 16; i++)
                    vv[i] = fmaxf(vv[i] * vec0[gcol + i] + vec1[gcol + i], 0.f);
            }
            if (EPI == 2 || EPI == 3) {
                const float rb = vec0[grow];
#pragma unroll
                for (int i = 0; i < 16; i++) vv[i] += rb;
            }
            if (EPI == 3 || EPI == 4) {
#pragma unroll
                for (int i = 0; i < 16; i += 4) {
                    f32x4 q = { vv[i], vv[i + 1], vv[i + 2], vv[i + 3] };
                    *(f32x4*)&Cf[(size_t)grow * ldc + gcol + i] = q;
                }
            } else {
                uint4 q0 = { cvtpk(vv[0], vv[1]), cvtpk(vv[2], vv[3]),
                             cvtpk(vv[4], vv[5]), cvtpk(vv[6], vv[7]) };
                uint4 q1 = { cvtpk(vv[8], vv[9]), cvtpk(vv[10], vv[11]),
                             cvtpk(vv[12], vv[13]), cvtpk(vv[14], vv[15]) };
                *(uint4*)&Cu[(size_t)grow * ldc + gcol] = q0;
                *(uint4*)&Cu[(size_t)grow * ldc + gcol + 8] = q1;
            }
        }
        __syncthreads();
    }
}

// thin wrappers
template <int EPI>
__global__ __launch_bounds__(256) void gemm_nt(
    const ushort* __restrict__ A, const ushort* __restrict__ B, void* __restrict__ Cout,
    int K, int lda, int ldb, int ldc,
    size_t zsa, size_t zsb, size_t zsc,
    const float* __restrict__ vec0, const float* __restrict__ vec1,
    float* __restrict__ rsum) {
    __shared__ __align__(16) ushort smem[6 * 4096];
    if (EPI == 6 && blockIdx.x < blockIdx.y) return;
    gemm_body<EPI>(blockIdx.x, blockIdx.y, blockIdx.z, A, B, Cout, K, lda, ldb, ldc,
                   zsa, zsb, zsc, vec0, vec1, rsum, smem);
}

// ---------------- combo: Kt GEMM + V GEMM in one dispatch (independent) ----------------
__global__ __launch_bounds__(256) void k_kv(
    const ushort* __restrict__ Xt, const ushort* __restrict__ wkb,
    const ushort* __restrict__ wvb, ushort* __restrict__ Kt, ushort* __restrict__ V,
    const float* __restrict__ scaleA, const float* __restrict__ shiftA,
    const float* __restrict__ bv) {
    __shared__ __align__(16) ushort smem[6 * 4096];
    const int id = blockIdx.x;
    if (id < 200) {        // Kt: grid (2,50,2)
        gemm_body<1>(id & 1, (id >> 1) % 50, id / 100, Xt, wkb, Kt,
                     512, 512, 512, 256, 3276800, 0, 1638400, scaleA, shiftA, nullptr, smem);
    } else {               // V: grid (50,2,2)
        const int i = id - 200;
        gemm_body<2>(i % 50, (i / 50) % 2, i / 100, wvb, Xt, V,
                     512, 512, 512, 6400, 0, 3276800, 1638400, bv, nullptr, nullptr, smem);
    }
}

// ---------------- combo: PV(batch 0) + symmetric-S(batch 1) in one dispatch ----------------
// PV0 reads S0 (~2.9 TB/s), S1 writes S1 (~2.9 TB/s) — disjoint buffers, combined
// demand < 6.3 TB/s ceiling, so they co-run instead of queueing. PV blocks first
// so the BW stream starts immediately; S blocks backfill.
__global__ __launch_bounds__(256) void k_pv_s(
    const ushort* __restrict__ S0, const ushort* __restrict__ V0, float* __restrict__ part,
    const ushort* __restrict__ Kt1, ushort* __restrict__ S1, float* __restrict__ rowsum1) {
    __shared__ __align__(16) ushort smem[6 * 4096];
    const int id = blockIdx.x;
    if (id < 500) {        // PV b=0: grid (2,50,5)
        gemm_body<4>(id & 1, (id >> 1) % 50, id / 100, S0, V0, part,
                     1280, 6400, 6400, 256, 1280, 1280, 1638400, nullptr, nullptr, nullptr, smem);
    } else {               // S b=1: grid (50,50), upper triangle only
        const int sid = id - 500;
        const int sx = sid % 50, sy = sid / 50;
        if (sx < sy) return;
        gemm_body<6>(sx, sy, 0, Kt1, Kt1, S1,
                     256, 256, 256, 6400, 0, 0, 0, nullptr, nullptr, rowsum1, smem);
    }
}

// ---------------- split-K reduce + inline softmax normalizer ----------------
__global__ __launch_bounds__(256) void reduce_ctx(const float* __restrict__ part, ushort* __restrict__ ctx,
                                                  const float* __restrict__ rsum) {
    const size_t CH = 1638400;  // elems per chunk
    size_t i = ((size_t)blockIdx.x * 256 + threadIdx.x) * 4;
    float4 a = *(const float4*)&part[i];
#pragma unroll
    for (int c = 1; c < 5; c++) {
        float4 s = *(const float4*)&part[i + (size_t)c * CH];
        a.x += s.x; a.y += s.y; a.z += s.z; a.w += s.w;
    }
    const int row = (int)(i >> 8);  // 256 cols per row
    float s = 0.f;
#pragma unroll
    for (int xb = 0; xb < 50; xb++) s += rsum[(size_t)xb * 6400 + row];
    const float w = 1.f / s;
    uint2 o = { cvtpk(a.x * w, a.y * w), cvtpk(a.z * w, a.w * w) };
    *(uint2*)&ctx[i] = o;
}

// ---------------- host ----------------
extern "C" void kernel_launch(void* const* d_in, const int* in_sizes, int n_in,
                              void* d_out, int out_size, void* d_ws, size_t ws_size,
                              hipStream_t stream) {
    (void)in_sizes; (void)n_in; (void)out_size; (void)ws_size;
    const float* x     = (const float*)d_in[0];
    const float* wk    = (const float*)d_in[1];
    const float* bk    = (const float*)d_in[2];
    const float* gamma = (const float*)d_in[3];
    const float* beta  = (const float*)d_in[4];
    const float* rmean = (const float*)d_in[5];
    const float* rvar  = (const float*)d_in[6];
    const float* wv    = (const float*)d_in[7];
    const float* bv    = (const float*)d_in[8];
    const float* wW    = (const float*)d_in[9];
    const float* bW    = (const float*)d_in[10];
    float* out = (float*)d_out;

    // workspace layout (ushort elements) — ~233 MB
    ushort* Xt   = (ushort*)d_ws;          // 2*6400*512   = 6,553,600
    ushort* wkb  = Xt + 6553600;           // 131,072
    ushort* wvb  = wkb + 131072;           // 131,072
    ushort* wWb  = wvb + 131072;           // 131,072
    ushort* Kt   = wWb + 131072;           // 2*6400*256   = 3,276,800
    ushort* V    = Kt + 3276800;           // 3,276,800
    ushort* ctxT = V + 3276800;            // 3,276,800
    ushort* S0   = ctxT + 3276800;         // 6400*6400    = 40,960,000 (batch 0)
    ushort* S1   = S0 + 40960000;          // 40,960,000 (batch 1)
    float* scaleA = (float*)(S1 + 40960000);
    float* shiftA = scaleA + 256;
    float* rowsum0 = shiftA + 256;         // 50*6400 = 320,000 f32
    float* rowsum1 = rowsum0 + 320000;     // 320,000 f32
    float* part   = rowsum1 + 320000;      // 5*6400*256 f32 = 8,192,000 f32 (33 MB)

    prep_all<<<1537, 256, 0, stream>>>(wk, wv, wW, bk, gamma, beta, rmean, rvar,
                                       wkb, wvb, wWb, scaleA, shiftA);
    transpose_cvt<<<dim3(200, 16, 2), dim3(32, 32), 0, stream>>>(x, Xt);

    // Kt (both batches) + V (both batches) — one combined dispatch, 400 blocks
    k_kv<<<400, 256, 0, stream>>>(Xt, wkb, wvb, Kt, V, scaleA, shiftA, bv);

    ushort* Kt0 = Kt;
    ushort* Kt1 = Kt + 1638400;
    ushort* V0b = V;
    ushort* V1b = V + 1638400;

    // S0 = exp(Kt0 . Kt0^T), symmetric upper-tri + mirror (round-11 validated)
    gemm_nt<6><<<dim3(50, 50), 256, 0, stream>>>(Kt0, Kt0, S0, 256, 256, 256, 6400,
                                                 0, 0, 0, nullptr, nullptr, rowsum0);

    // PV0 (reads S0 -> part) || S1 (Kt1 -> S1, rowsum1): combined dispatch, 3000 blocks
    k_pv_s<<<3000, 256, 0, stream>>>(S0, V0b, part, Kt1, S1, rowsum1);

    // red0: part + rowsum0 -> ctxT0
    reduce_ctx<<<1600, 256, 0, stream>>>(part, ctxT, rowsum0);

    // PV1: S1 . V1^T -> part (part free after red0)
    gemm_nt<4><<<dim3(2, 50, 5), 256, 0, stream>>>(S1, V1b, part, 1280, 6400, 6400, 256,
                                                   1280, 1280, 1638400, nullptr, nullptr, nullptr);

    // red1: part + rowsum1 -> ctxT1
    reduce_ctx<<<1600, 256, 0, stream>>>(part, ctxT + 1638400, rowsum1);

    // out[b][o][n] = wW . ctxT^T + bW — both batches in one dispatch
    gemm_nt<3><<<dim3(50, 4, 2), 256, 0, stream>>>(wWb, ctxT, out, 256, 256, 256, 6400,
                                                   0, 1638400, 3276800, bW, nullptr, nullptr);
}

// Round 15
// 291.108 us; speedup vs baseline: 1.1283x; 1.0217x over previous
//
#include <hip/hip_runtime.h>
#include <stdint.h>

typedef __attribute__((ext_vector_type(8))) short bf16x8;
typedef __attribute__((ext_vector_type(4))) float f32x4;

__device__ __forceinline__ ushort f2bf(float f) {
    union { float f; uint32_t i; } v; v.f = f;
    uint32_t r = v.i + 0x7fff + ((v.i >> 16) & 1);
    return (ushort)(r >> 16);
}
__device__ __forceinline__ uint32_t cvtpk(float lo, float hi) {
    uint32_t r;
    asm("v_cvt_pk_bf16_f32 %0, %1, %2" : "=v"(r) : "v"(lo), "v"(hi));
    return r;
}

typedef unsigned int uint_as1 __attribute__((address_space(1)));
typedef unsigned int uint_as3 __attribute__((address_space(3)));
__device__ __forceinline__ void async16(const void* g, void* l) {
    __builtin_amdgcn_global_load_lds((const uint_as1*)g, (uint_as3*)l, 16, 0, 0);
}

// ---------------- merged prep: weight cvt x3 + BN fold (one dispatch) ----------------
__global__ void prep_all(const float* __restrict__ wk, const float* __restrict__ wv,
                         const float* __restrict__ wW,
                         const float* __restrict__ bk, const float* __restrict__ gamma,
                         const float* __restrict__ beta, const float* __restrict__ rmean,
                         const float* __restrict__ rvar,
                         ushort* __restrict__ wkb, ushort* __restrict__ wvb,
                         ushort* __restrict__ wWb,
                         float* __restrict__ scaleA, float* __restrict__ shiftA) {
    const int b = blockIdx.x;
    if (b == 1536) {
        int i = threadIdx.x;   // 256 threads
        float s = gamma[i] * rsqrtf(rvar[i] + 1e-5f);
        scaleA[i] = 0.25f * s;                                // fold Ck^-0.5 = 1/16 as 0.25 per operand
        shiftA[i] = 0.25f * ((bk[i] - rmean[i]) * s + beta[i]);
        return;
    }
    const int i = (b & 511) * 256 + threadIdx.x;   // 512 blocks x 256 = 131072 per tensor
    const float* src = (b < 512) ? wk : (b < 1024) ? wv : wW;
    ushort* dst = (b < 512) ? wkb : (b < 1024) ? wvb : wWb;
    dst[i] = f2bf(src[i]);
}

// x [b][512][6400] f32  ->  Xt [b][6400][512] bf16
__global__ void transpose_cvt(const float* __restrict__ x, ushort* __restrict__ xt) {
    __shared__ float t[32][33];
    int b = blockIdx.z;
    int n0 = blockIdx.x * 32, c0 = blockIdx.y * 32;
    const float* xb = x + (size_t)b * 512 * 6400;
    ushort* xtb = xt + (size_t)b * 6400 * 512;
    int tx = threadIdx.x, ty = threadIdx.y;
    t[ty][tx] = xb[(size_t)(c0 + ty) * 6400 + n0 + tx];
    __syncthreads();
    xtb[(size_t)(n0 + ty) * 512 + c0 + tx] = f2bf(t[tx][ty]);
}

// ---------------- unified NT GEMM body: C[i][j] = sum_k A[i][k]*B[j][k] ----------------
// Round-6 core upgraded to 2-tiles-per-epoch: 128x128 tile, 4 waves, BK=32,
// 4 LDS buffers (two ping-pong pairs, 64 KB). Per epoch: vmcnt(0) (drains the
// pair issued one full epoch of compute earlier — same cycle-cover as the old
// vmcnt(4)/2-ahead since one epoch = two old K-steps), raw s_barrier, stage
// next pair into the pair freed by epoch e-1 (after-barrier => all reads done),
// then 2x(8 ds_read_b128 + 16 MFMA). Half the barrier+drain events of round 14.
// Quarter-swizzle unchanged (SQ_LDS_BANK_CONFLICT = 0). nT must be EVEN.
// EPI 1: bf16 store relu(acc*vec0[col] + vec1[col])   (col-affine, BN+ReLU for Kt)
// EPI 2: bf16 store acc + vec0[row]                   (row bias, V)
// EPI 3: f32  store acc + vec0[row]                   (row bias, final out)
// EPI 4: f32  store raw                               (split-K partials, PV)
// EPI 6: SYMMETRIC exp tile (round-11 validated): caller filters bx >= by;
//        store exp(acc) tile AND mirror; rsum[bx][rows] / rsum[by][cols] partials.
template <int EPI>
__device__ __forceinline__ void gemm_body(
    int bxi, int byi, int bzi,
    const ushort* __restrict__ A, const ushort* __restrict__ B, void* __restrict__ Cout,
    int K, int lda, int ldb, int ldc,
    size_t zsa, size_t zsb, size_t zsc,
    const float* __restrict__ vec0, const float* __restrict__ vec1,
    float* __restrict__ rsum, ushort* smem) {

    A += (size_t)bzi * zsa;
    B += (size_t)bzi * zsb;

    const int tid = threadIdx.x;
    const int lane = tid & 63, wave = tid >> 6;
    const int wm = wave & 1, wn = wave >> 1;
    const int bM = byi * 128, bN = bxi * 128;

    const int sr = lane >> 2;
    const int scs = ((lane & 3) ^ ((lane >> 3) & 3)) * 8;
    const ushort* gA0 = A + (size_t)(bM + wave * 32 + sr) * lda + scs;
    const ushort* gA1 = gA0 + (size_t)16 * lda;
    const ushort* gB0 = B + (size_t)(bN + wave * 32 + sr) * ldb + scs;
    const ushort* gB1 = gB0 + (size_t)16 * ldb;
    ushort* lAw = &smem[wave * 1024];              // + buf*4096, bufs 0..3
    ushort* lBw = &smem[4 * 4096 + wave * 1024];   // + buf*4096

    const int rowA = wm * 64;
    const int rowB = wn * 64;
    const int fr = lane & 15;
    const int fk = ((lane >> 4) ^ ((fr >> 1) & 3)) * 8;

    f32x4 acc[4][4] = {};
    const int nT = K >> 5;     // EVEN for all call sites
    const int nE = nT >> 1;

    auto stage = [&](int t, int buf) {
        const int k0 = t * 32;
        const int ob = buf * 4096;
        async16(gA0 + k0, lAw + ob);
        async16(gA1 + k0, lAw + ob + 512);
        async16(gB0 + k0, lBw + ob);
        async16(gB1 + k0, lBw + ob + 512);
    };

    // prologue: epoch 0 -> bufs {0,1}
    stage(0, 0);
    stage(1, 1);

    for (int e = 0; e < nE; ++e) {
        asm volatile("s_waitcnt vmcnt(0)" ::: "memory");   // epoch e's 8 loads
        __builtin_amdgcn_sched_barrier(0);
        __builtin_amdgcn_s_barrier();
        __builtin_amdgcn_sched_barrier(0);
        if (e + 1 < nE) {   // pair freed by epoch e-1 == pair (e+1)&1
            const int p = ((e + 1) & 1) * 2;
            stage(2 * e + 2, p);
            stage(2 * e + 3, p + 1);
        }
        const int pc = (e & 1) * 2;
#pragma unroll
        for (int h = 0; h < 2; ++h) {
            const ushort* lA = &smem[(pc + h) * 4096];
            const ushort* lB = &smem[4 * 4096 + (pc + h) * 4096];
            bf16x8 af[4], bff[4];
#pragma unroll
            for (int mi = 0; mi < 4; mi++)
                af[mi] = *(const bf16x8*)&lA[(rowA + mi * 16 + fr) * 32 + fk];
#pragma unroll
            for (int ni = 0; ni < 4; ni++)
                bff[ni] = *(const bf16x8*)&lB[(rowB + ni * 16 + fr) * 32 + fk];
#pragma unroll
            for (int mi = 0; mi < 4; mi++)
#pragma unroll
                for (int ni = 0; ni < 4; ni++)
                    acc[mi][ni] = __builtin_amdgcn_mfma_f32_16x16x32_bf16(af[mi], bff[ni], acc[mi][ni], 0, 0, 0);
        }
        __builtin_amdgcn_sched_barrier(0);
    }
    __builtin_amdgcn_s_barrier();
    __builtin_amdgcn_sched_barrier(0);

    // ---- epilogue: repack through LDS, store full lines ----
    float* Cf = (float*)Cout + (size_t)bzi * zsc;
    ushort* Cu = (ushort*)Cout + (size_t)bzi * zsc;
    float* lt = (float*)smem;
    const int g4 = (lane >> 4) * 4;
    const int cl = lane & 15;
    const int lr = tid >> 3;
    const int ch = tid & 7;

    if (EPI == 6) {
        const bool diag = (bxi == byi);
        float creg[16];
#pragma unroll
        for (int i = 0; i < 16; i++) creg[i] = 0.f;
#pragma unroll
        for (int mi = 0; mi < 4; ++mi) {
#pragma unroll
            for (int ni = 0; ni < 4; ++ni) {
                const int lcol = wn * 64 + ni * 16 + cl;
#pragma unroll
                for (int r = 0; r < 4; ++r)
                    lt[(wm * 16 + g4 + r) * 132 + lcol] = acc[mi][ni][r];
            }
            __syncthreads();
            const int brow = (lr < 16) ? (mi * 16 + lr) : (64 + mi * 16 + (lr - 16));
            const int grow = bM + brow;
            const int gcol = bN + ch * 16;
            float vv[16];
#pragma unroll
            for (int i = 0; i < 16; i += 4) {
                f32x4 q = *(const f32x4*)&lt[lr * 132 + ch * 16 + i];
                vv[i] = __expf(q[0]); vv[i + 1] = __expf(q[1]);
                vv[i + 2] = __expf(q[2]); vv[i + 3] = __expf(q[3]);
            }
            float ssum = 0.f;
#pragma unroll
            for (int i = 0; i < 16; i++) { ssum += vv[i]; creg[i] += vv[i]; }
            ssum += __shfl_down(ssum, 4, 8);
            ssum += __shfl_down(ssum, 2, 8);
            ssum += __shfl_down(ssum, 1, 8);
            if (ch == 0) rsum[(size_t)bxi * 6400 + grow] = ssum;
            uint4 q0 = { cvtpk(vv[0], vv[1]), cvtpk(vv[2], vv[3]),
                         cvtpk(vv[4], vv[5]), cvtpk(vv[6], vv[7]) };
            uint4 q1 = { cvtpk(vv[8], vv[9]), cvtpk(vv[10], vv[11]),
                         cvtpk(vv[12], vv[13]), cvtpk(vv[14], vv[15]) };
            *(uint4*)&Cu[(size_t)grow * ldc + gcol] = q0;
            *(uint4*)&Cu[(size_t)grow * ldc + gcol + 8] = q1;
            if (!diag) {
#pragma unroll
                for (int i = 0; i < 16; i++) lt[lr * 132 + ch * 16 + i] = vv[i];
                __syncthreads();
                const int j = tid >> 1, h = tid & 1;
                ushort mo[16];
#pragma unroll
                for (int i = 0; i < 16; i += 2) {
                    float a = lt[(h * 16 + i) * 132 + j];
                    float b2 = lt[(h * 16 + i + 1) * 132 + j];
                    *(uint32_t*)&mo[i] = cvtpk(a, b2);
                }
                const size_t mbase = (size_t)(bN + j) * ldc + bM + h * 64 + mi * 16;
                *(uint4*)&Cu[mbase] = *(const uint4*)&mo[0];
                *(uint4*)&Cu[mbase + 8] = *(const uint4*)&mo[8];
            }
            __syncthreads();
        }
        if (!diag) {
#pragma unroll
            for (int i = 0; i < 16; i++) lt[lr * 132 + ch * 16 + i] = creg[i];
            __syncthreads();
            if (tid < 128) {
                float s = 0.f;
#pragma unroll
                for (int r = 0; r < 32; r++) s += lt[r * 132 + tid];
                rsum[(size_t)byi * 6400 + bN + tid] = s;
            }
        }
        return;
    }

#pragma unroll
    for (int mi = 0; mi < 4; ++mi) {
#pragma unroll
        for (int ni = 0; ni < 4; ++ni) {
            const int lcol = wn * 64 + ni * 16 + cl;
#pragma unroll
            for (int r = 0; r < 4; ++r)
                lt[(wm * 16 + g4 + r) * 132 + lcol] = acc[mi][ni][r];
        }
        __syncthreads();
        {
            const int brow = (lr < 16) ? (mi * 16 + lr) : (64 + mi * 16 + (lr - 16));
            const int grow = bM + brow;
            const int gcol = bN + ch * 16;
            float vv[16];
#pragma unroll
            for (int i = 0; i < 16; i += 4) {
                f32x4 q = *(const f32x4*)&lt[lr * 132 + ch * 16 + i];
                vv[i] = q[0]; vv[i + 1] = q[1]; vv[i + 2] = q[2]; vv[i + 3] = q[3];
            }
            if (EPI == 1) {
#pragma unroll
                for (int i = 0; i < 16; i++)
                    vv[i] = fmaxf(vv[i] * vec0[gcol + i] + vec1[gcol + i], 0.f);
            }
            if (EPI == 2 || EPI == 3) {
                const float rb = vec0[grow];
#pragma unroll
                for (int i = 0; i < 16; i++) vv[i] += rb;
            }
            if (EPI == 3 || EPI == 4) {
#pragma unroll
                for (int i = 0; i < 16; i += 4) {
                    f32x4 q = { vv[i], vv[i + 1], vv[i + 2], vv[i + 3] };
                    *(f32x4*)&Cf[(size_t)grow * ldc + gcol + i] = q;
                }
            } else {
                uint4 q0 = { cvtpk(vv[0], vv[1]), cvtpk(vv[2], vv[3]),
                             cvtpk(vv[4], vv[5]), cvtpk(vv[6], vv[7]) };
                uint4 q1 = { cvtpk(vv[8], vv[9]), cvtpk(vv[10], vv[11]),
                             cvtpk(vv[12], vv[13]), cvtpk(vv[14], vv[15]) };
                *(uint4*)&Cu[(size_t)grow * ldc + gcol] = q0;
                *(uint4*)&Cu[(size_t)grow * ldc + gcol + 8] = q1;
            }
        }
        __syncthreads();
    }
}

// thin wrappers (each owns the 64 KB LDS)
template <int EPI>
__global__ __launch_bounds__(256) void gemm_nt(
    const ushort* __restrict__ A, const ushort* __restrict__ B, void* __restrict__ Cout,
    int K, int lda, int ldb, int ldc,
    size_t zsa, size_t zsb, size_t zsc,
    const float* __restrict__ vec0, const float* __restrict__ vec1,
    float* __restrict__ rsum) {
    __shared__ __align__(16) ushort smem[8 * 4096];
    gemm_body<EPI>(blockIdx.x, blockIdx.y, blockIdx.z, A, B, Cout, K, lda, ldb, ldc,
                   zsa, zsb, zsc, vec0, vec1, rsum, smem);
}

// ---------------- combo: Kt GEMM + V GEMM in one dispatch (independent) ----------------
__global__ __launch_bounds__(256) void k_kv(
    const ushort* __restrict__ Xt, const ushort* __restrict__ wkb,
    const ushort* __restrict__ wvb, ushort* __restrict__ Kt, ushort* __restrict__ V,
    const float* __restrict__ scaleA, const float* __restrict__ shiftA,
    const float* __restrict__ bv) {
    __shared__ __align__(16) ushort smem[8 * 4096];
    const int id = blockIdx.x;
    if (id < 200) {        // Kt: grid (2,50,2)
        gemm_body<1>(id & 1, (id >> 1) % 50, id / 100, Xt, wkb, Kt,
                     512, 512, 512, 256, 3276800, 0, 1638400, scaleA, shiftA, nullptr, smem);
    } else {               // V: grid (50,2,2)
        const int i = id - 200;
        gemm_body<2>(i % 50, (i / 50) % 2, i / 100, wvb, Xt, V,
                     512, 512, 512, 6400, 0, 3276800, 1638400, bv, nullptr, nullptr, smem);
    }
}

// ---------------- symmetric S, both batches: grid (50,50,2) ----------------
__global__ __launch_bounds__(256) void k_s_both(
    const ushort* __restrict__ Kt, ushort* __restrict__ S0, float* __restrict__ rowsum) {
    __shared__ __align__(16) ushort smem[8 * 4096];
    if (blockIdx.x < blockIdx.y) return;   // upper triangle only
    const int z = blockIdx.z;
    const ushort* K = Kt + (size_t)z * 1638400;
    ushort* S = S0 + (size_t)z * 40960000;
    float* rs = rowsum + (size_t)z * 320000;
    gemm_body<6>(blockIdx.x, blockIdx.y, 0, K, K, S,
                 256, 256, 256, 6400, 0, 0, 0, nullptr, nullptr, rs, smem);
}

// ---------------- PV, both batches, split-K x4: grid (2,50,8), z = b*4 + c ----------------
__global__ __launch_bounds__(256) void k_pv_both(
    const ushort* __restrict__ S0, const ushort* __restrict__ V, float* __restrict__ part) {
    __shared__ __align__(16) ushort smem[8 * 4096];
    const int z = blockIdx.z;
    const int b = z >> 2, c = z & 3;
    const ushort* A = S0 + (size_t)b * 40960000 + (size_t)c * 1600;
    const ushort* B = V + (size_t)b * 1638400 + (size_t)c * 1600;
    float* C = part + (size_t)b * 6553600 + (size_t)c * 1638400;
    gemm_body<4>(blockIdx.x, blockIdx.y, 0, A, B, C,
                 1600, 6400, 6400, 256, 0, 0, 0, nullptr, nullptr, nullptr, smem);
}

// ---------------- split-K reduce + inline normalizer, both batches (3200 blocks) ----------------
__global__ __launch_bounds__(256) void reduce_both(const float* __restrict__ part,
                                                   ushort* __restrict__ ctx,
                                                   const float* __restrict__ rowsum) {
    const int id = blockIdx.x;
    const int b = id >= 1600;
    const int lid = id - b * 1600;
    const float* p = part + (size_t)b * 6553600;
    const float* rs = rowsum + (size_t)b * 320000;
    ushort* cx = ctx + (size_t)b * 1638400;
    size_t i = ((size_t)lid * 256 + threadIdx.x) * 4;
    float4 a = *(const float4*)&p[i];
#pragma unroll
    for (int c = 1; c < 4; c++) {
        float4 s = *(const float4*)&p[i + (size_t)c * 1638400];
        a.x += s.x; a.y += s.y; a.z += s.z; a.w += s.w;
    }
    const int row = (int)(i >> 8);  // 256 cols per row
    float s = 0.f;
#pragma unroll
    for (int xb = 0; xb < 50; xb++) s += rs[(size_t)xb * 6400 + row];
    const float w = 1.f / s;
    uint2 o = { cvtpk(a.x * w, a.y * w), cvtpk(a.z * w, a.w * w) };
    *(uint2*)&cx[i] = o;
}

// ---------------- host ----------------
extern "C" void kernel_launch(void* const* d_in, const int* in_sizes, int n_in,
                              void* d_out, int out_size, void* d_ws, size_t ws_size,
                              hipStream_t stream) {
    (void)in_sizes; (void)n_in; (void)out_size; (void)ws_size;
    const float* x     = (const float*)d_in[0];
    const float* wk    = (const float*)d_in[1];
    const float* bk    = (const float*)d_in[2];
    const float* gamma = (const float*)d_in[3];
    const float* beta  = (const float*)d_in[4];
    const float* rmean = (const float*)d_in[5];
    const float* rvar  = (const float*)d_in[6];
    const float* wv    = (const float*)d_in[7];
    const float* bv    = (const float*)d_in[8];
    const float* wW    = (const float*)d_in[9];
    const float* bW    = (const float*)d_in[10];
    float* out = (float*)d_out;

    // workspace layout (ushort elements) — ~252 MB
    ushort* Xt   = (ushort*)d_ws;          // 2*6400*512   = 6,553,600
    ushort* wkb  = Xt + 6553600;           // 131,072
    ushort* wvb  = wkb + 131072;           // 131,072
    ushort* wWb  = wvb + 131072;           // 131,072
    ushort* Kt   = wWb + 131072;           // 2*6400*256   = 3,276,800
    ushort* V    = Kt + 3276800;           // 3,276,800
    ushort* ctxT = V + 3276800;            // 3,276,800
    ushort* S0   = ctxT + 3276800;         // 2 * 40,960,000 (S per batch)
    float* scaleA = (float*)(S0 + 2 * 40960000);
    float* shiftA = scaleA + 256;
    float* rowsum = shiftA + 256;          // 2 * 320,000 f32
    float* part   = rowsum + 640000;       // 2 * 4 * 1,638,400 f32 = 13,107,200 f32 (52 MB)

    prep_all<<<1537, 256, 0, stream>>>(wk, wv, wW, bk, gamma, beta, rmean, rvar,
                                       wkb, wvb, wWb, scaleA, shiftA);
    transpose_cvt<<<dim3(200, 16, 2), dim3(32, 32), 0, stream>>>(x, Xt);

    // Kt (both batches) + V (both batches) — one combined dispatch, 400 blocks
    k_kv<<<400, 256, 0, stream>>>(Xt, wkb, wvb, Kt, V, scaleA, shiftA, bv);

    // S_b = exp(Kt_b . Kt_b^T), symmetric upper-tri + mirror, both batches
    k_s_both<<<dim3(50, 50, 2), 256, 0, stream>>>(Kt, S0, rowsum);

    // ctxT partials: P_unnorm . V^T, split-K x4, both batches (800 blocks)
    k_pv_both<<<dim3(2, 50, 8), 256, 0, stream>>>(S0, V, part);

    // reduce + normalize, both batches
    reduce_both<<<3200, 256, 0, stream>>>(part, ctxT, rowsum);

    // out[b][o][n] = wW . ctxT^T + bW — both batches in one dispatch
    gemm_nt<3><<<dim3(50, 4, 2), 256, 0, stream>>>(wWb, ctxT, out, 256, 256, 256, 6400,
                                                   0, 1638400, 3276800, bW, nullptr, nullptr);
}